// Round 11
// baseline (2283.985 us; speedup 1.0000x reference)
//
#include <hip/hip_runtime.h>
#include <stdint.h>

// SuperRGCNLayer on MI355X — round 11 (identical to rounds 8-10; GPU unavailable).
// Fixes vs round 7 (1299us k_main, occupancy 11%, phase-B W-VMEM storm):
//  - DPB 32->16, LDS ~50KB -> 3 blocks/CU.
//  - dsts sorted by node_type: every block's dsts share one dt -> W staged
//    per-r8 into LDS (128 VMEM instrs/block vs 4096), read as LDS broadcast.
// ws need ~8.3 MB (proven ws >= 16.26 MB in round 1).

#define TPB 256
#define DPB 16          // dsts per k_main block
#define ASTR (8*64 + 4) // A8 per-dst stride: +4 skew spreads re-rows over banks

// ---- Wt[m][i][o] = sum_b w_comp[o%16][b] * weight[(m*4+o/16)*512 + b*64 + i]
__global__ void k_build_w(const float* __restrict__ weight,
                          const float* __restrict__ w_comp,
                          float* __restrict__ Wt) {
  const int idx = blockIdx.x * TPB + threadIdx.x;
  if (idx >= 16 * 64 * 64) return;
  const int m = idx >> 12, i = (idx >> 6) & 63, o = idx & 63;
  const float* wc = w_comp + ((o & 15) << 3);
  const float* wf = weight + (((m << 2) + (o >> 4)) << 9) + i;
  float s = 0.f;
#pragma unroll
  for (int b = 0; b < 8; ++b) s = fmaf(wc[b], wf[b << 6], s);
  Wt[idx] = s;
}

__global__ void k_zero(int* __restrict__ p, int n) {
  const int i = blockIdx.x * 1024 + threadIdx.x;
  if (i < n) p[i] = 0;
}

// per-dst edge histogram
__global__ void k_hist(const int* __restrict__ edst, int* __restrict__ cntD, int E) {
  const int e = blockIdx.x * TPB + threadIdx.x;
  if (e < E) atomicAdd(&cntD[edst[e]], 1);
}

// node-type histogram (typeCnt = cntD + N, zeroed by k_zero over N+2)
__global__ void k_typehist(const int* __restrict__ nt, int* __restrict__ typeCnt, int N) {
  const int i = blockIdx.x * TPB + threadIdx.x;
  if (i < N) atomicAdd(&typeCnt[nt[i]], 1);
}

// single-block exclusive scan over N bins -> offsD[N+1], cursor; also type-scan
#define SCAN_T 1024
__global__ void k_scan(const int* __restrict__ cnt, int* __restrict__ offs,
                       int* __restrict__ cursor, const int* __restrict__ typeCnt,
                       int* __restrict__ tblk, int N) {
  __shared__ int ps[SCAN_T];
  const int tid = threadIdx.x;
  const int chunk = (N + SCAN_T - 1) / SCAN_T;
  const int b = tid * chunk, e = min(b + chunk, N);
  int s = 0;
  for (int i = b; i < e; ++i) s += cnt[i];
  ps[tid] = s;
  __syncthreads();
  for (int off = 1; off < SCAN_T; off <<= 1) {
    int v = 0;
    if (tid >= off) v = ps[tid - off];
    __syncthreads();
    ps[tid] += v;
    __syncthreads();
  }
  int run = (tid > 0) ? ps[tid - 1] : 0;
  for (int i = b; i < e; ++i) { offs[i] = run; cursor[i] = run; run += cnt[i]; }
  if (tid == SCAN_T - 1) offs[N] = run;
  if (tid == 0) { tblk[0] = typeCnt[0]; tblk[1] = 0; tblk[2] = typeCnt[0]; }
}

// dstPerm: type-0 dsts first, then type-1
__global__ void k_typescatter(const int* __restrict__ nt, int* __restrict__ tcur,
                              int* __restrict__ dstPerm, int N) {
  const int i = blockIdx.x * TPB + threadIdx.x;
  if (i < N) {
    const int pos = atomicAdd(&tcur[nt[i]], 1);
    dstPerm[pos] = i;
  }
}

// edges sorted by dst: packS[pos] = src | r8<<24
__global__ void k_scatter(const int* __restrict__ nt, const int* __restrict__ esrc,
                          const int* __restrict__ edst, const int* __restrict__ etyp,
                          int* __restrict__ cursor, uint32_t* __restrict__ packS, int E) {
  const int e = blockIdx.x * TPB + threadIdx.x;
  if (e < E) {
    const int s = esrc[e];
    const uint32_t r8 = (uint32_t)(nt[s] * 4 + etyp[e]);
    const int pos = atomicAdd(&cursor[edst[e]], 1);
    packS[pos] = (uint32_t)s | (r8 << 24);
  }
}

// ---- main fused kernel ----------------------------------------------------
__global__ __launch_bounds__(TPB, 3) void k_main(
    const float* __restrict__ x, const float* __restrict__ Wt,
    const int* __restrict__ offsD, const uint32_t* __restrict__ packS,
    const int* __restrict__ dstPerm, const int* __restrict__ tblk,
    const float* __restrict__ bias, float* __restrict__ out, int N) {
  __shared__ float A8[DPB * ASTR];   // 33 KB: [dst][r8*64 + k], +4/dst skew
  __shared__ float Wl[64 * 64];      // 16 KB: staged W[rel] for current r8
  __shared__ int dstl[DPB], offA[DPB], offB[DPB];
  __shared__ int shn0;
  const int tid = threadIdx.x;
  if (tid == 0) shn0 = tblk[0];
  __syncthreads();
  const int n0 = shn0;
  const int nb0 = (n0 + DPB - 1) / DPB;
  const int nb1 = (N - n0 + DPB - 1) / DPB;
  int t, base, cnt;
  if ((int)blockIdx.x < nb0) {
    t = 0; base = blockIdx.x * DPB; cnt = min(DPB, n0 - base);
  } else if ((int)blockIdx.x < nb0 + nb1) {
    t = 1; base = n0 + (blockIdx.x - nb0) * DPB; cnt = min(DPB, N - base);
  } else {
    return;
  }
  if (tid < cnt) {
    const int d = dstPerm[base + tid];
    dstl[tid] = d;
    offA[tid] = offsD[d];
    offB[tid] = offsD[d + 1];
  }
  __syncthreads();

  // ---- phase A: per-dst segment sums (wave-per-dst; 4 dsts/wave)
  const int w = tid >> 6, lane = tid & 63;
  for (int ld = w; ld < DPB; ld += 4) {
    float racc[8] = {0.f, 0.f, 0.f, 0.f, 0.f, 0.f, 0.f, 0.f};
    if (ld < cnt) {
      const int j0 = offA[ld], j1 = offB[ld];
      for (int j = j0; j < j1; j += 8) {
        uint32_t pk[8];
        float xv[8];
#pragma unroll
        for (int u = 0; u < 8; ++u) {
          const int jj = min(j + u, j1 - 1);
          pk[u] = packS[jj];
        }
#pragma unroll
        for (int u = 0; u < 8; ++u)
          xv[u] = x[((size_t)(pk[u] & 0x00FFFFFFu) << 6) + lane];
#pragma unroll
        for (int u = 0; u < 8; ++u) {
          const float v = (j + u < j1) ? xv[u] : 0.f;
          switch (pk[u] >> 24) {  // wave-uniform branch
            case 0: racc[0] += v; break;
            case 1: racc[1] += v; break;
            case 2: racc[2] += v; break;
            case 3: racc[3] += v; break;
            case 4: racc[4] += v; break;
            case 5: racc[5] += v; break;
            case 6: racc[6] += v; break;
            default: racc[7] += v; break;
          }
        }
      }
    }
#pragma unroll
    for (int c = 0; c < 8; ++c) A8[ld * ASTR + c * 64 + lane] = racc[c];
  }
  // (first barrier inside the r8 loop publishes A8)

  // ---- phase B: out[16][64] = bias + sum_r8 A8[:,r8,:] @ W[rel(t,r8)]
  const int co = tid & 15, re = tid >> 4;  // thread = (dst re, col-quad co)
  const float4 bv = ((const float4*)bias)[co];
  float a0 = bv.x, a1 = bv.y, a2 = bv.z, a3 = bv.w;
#pragma unroll 1
  for (int r8 = 0; r8 < 8; ++r8) {
    const int rel = ((r8 >> 2) << 3) + (t << 2) + (r8 & 3);
    __syncthreads();  // prior r8's readers done (and A8 published on r8==0)
    {
      const float4* src = (const float4*)(Wt + (rel << 12));
      float4* dst4 = (float4*)Wl;
#pragma unroll
      for (int u = 0; u < 4; ++u) dst4[tid + (u << 8)] = src[tid + (u << 8)];
    }
    __syncthreads();  // Wl ready
    const float* arow = &A8[re * ASTR + (r8 << 6)];
#pragma unroll 4
    for (int k4 = 0; k4 < 64; k4 += 4) {
      const float4 av = *(const float4*)(arow + k4);
#pragma unroll
      for (int kk = 0; kk < 4; ++kk) {
        const float4 wv = *(const float4*)&Wl[((k4 + kk) << 6) + (co << 2)];
        const float f = ((const float*)&av)[kk];
        a0 = fmaf(f, wv.x, a0); a1 = fmaf(f, wv.y, a1);
        a2 = fmaf(f, wv.z, a2); a3 = fmaf(f, wv.w, a3);
      }
    }
  }
  if (re < cnt) {
    float4 v = {a0, a1, a2, a3};
    *(float4*)(out + ((size_t)dstl[re] << 6) + (co << 2)) = v;
  }
}

// ---- launch ---------------------------------------------------------------
extern "C" void kernel_launch(void* const* d_in, const int* in_sizes, int n_in,
                              void* d_out, int out_size, void* d_ws, size_t ws_size,
                              hipStream_t stream) {
  const float* x      = (const float*)d_in[0];
  const int* nt       = (const int*)d_in[1];
  const int* esrc     = (const int*)d_in[2];
  const int* edst     = (const int*)d_in[3];
  const int* etyp     = (const int*)d_in[4];
  const float* weight = (const float*)d_in[5];
  const float* w_comp = (const float*)d_in[6];
  const float* bias   = (const float*)d_in[7];
  float* out = (float*)d_out;
  const int N = in_sizes[1];
  const int E = in_sizes[2];

  char* wsp = (char*)d_ws;
  size_t off = 0;
  float* Wt       = (float*)(wsp + off); off += 262144;
  int* cntD       = (int*)(wsp + off); off += (size_t)(N + 2) * 4 + 8;  // +typeCnt[2]
  int* offsD      = (int*)(wsp + off); off += (size_t)(N + 1) * 4 + 12;
  int* cursor     = (int*)(wsp + off); off += (size_t)N * 4;
  int* tblk       = (int*)(wsp + off); off += 16;   // [n0, cur0, cur1, pad]
  int* dstPerm    = (int*)(wsp + off); off += (size_t)N * 4;
  uint32_t* packS = (uint32_t*)(wsp + off); off += (size_t)E * 4;
  if (ws_size < off) return;
  int* typeCnt = cntD + N;

  const int ebl = (E + TPB - 1) / TPB;
  const int nbl = (N + TPB - 1) / TPB;

  hipLaunchKernelGGL(k_zero, dim3((N + 2 + 1023) / 1024), dim3(1024), 0, stream, cntD, N + 2);
  hipLaunchKernelGGL(k_build_w, dim3(256), dim3(TPB), 0, stream, weight, w_comp, Wt);
  hipLaunchKernelGGL(k_hist, dim3(ebl), dim3(TPB), 0, stream, edst, cntD, E);
  hipLaunchKernelGGL(k_typehist, dim3(nbl), dim3(TPB), 0, stream, nt, typeCnt, N);
  hipLaunchKernelGGL(k_scan, dim3(1), dim3(SCAN_T), 0, stream, cntD, offsD, cursor,
                     typeCnt, tblk, N);
  hipLaunchKernelGGL(k_typescatter, dim3(nbl), dim3(TPB), 0, stream, nt, tblk + 1,
                     dstPerm, N);
  hipLaunchKernelGGL(k_scatter, dim3(ebl), dim3(TPB), 0, stream, nt, esrc, edst, etyp,
                     cursor, packS, E);
  hipLaunchKernelGGL(k_main, dim3(N / DPB + 2), dim3(TPB), 0, stream,
                     x, Wt, offsD, packS, dstPerm, tblk, bias, out, N);
}